// Round 5
// baseline (403.850 us; speedup 1.0000x reference)
//
#include <hip/hip_runtime.h>
#include <math.h>

#define NPTS 65536

using half8   = __attribute__((ext_vector_type(8))) _Float16;
using half4   = __attribute__((ext_vector_type(4))) _Float16;
using half2v  = __attribute__((ext_vector_type(2))) _Float16;
using floatx4 = __attribute__((ext_vector_type(4))) float;

// ---------------------------------------------------------------------------
// k_prep: weights -> f16 [64 d][1024 kc'] with kc' = c*16 + k (k=15 row zero);
//         features -> f16 table featH[N][64]
// ---------------------------------------------------------------------------
__global__ __launch_bounds__(256) void k_prep(
    const float* __restrict__ ow, const float* __restrict__ w,
    const float* __restrict__ feat,
    _Float16* __restrict__ owt, _Float16* __restrict__ wt,
    _Float16* __restrict__ featH)
{
  int b = blockIdx.x;
  if (b < 256) {                       // 256*256 == 65536 == 64*1024
    int i = b * 256 + threadIdx.x;
    int d = i >> 10, kc = i & 1023, c = kc >> 4, k = kc & 15;
    owt[i] = (k < 15 && d < 60) ? (_Float16)ow[(k * 64 + c) * 60 + d] : (_Float16)0.f;
    wt[i]  = (k < 15) ? (_Float16)w[(k * 64 + c) * 64 + d] : (_Float16)0.f;
  } else {                             // 4096*256 == 1048576 == N*64/4
    int j = (b - 256) * 256 + threadIdx.x;
    float4 f = ((const float4*)feat)[j];
    half4 h = {(_Float16)f.x, (_Float16)f.y, (_Float16)f.z, (_Float16)f.w};
    ((half4*)featH)[j] = h;
  }
}

// ---------------------------------------------------------------------------
// Fused deformable KPConv. 16 pts/block, 4 waves x 4 pts, 4 blocks/CU.
// fT row swizzle: physical row r' = c ^ ((c>>3)&1)  -> transpose dword writes
// span all 32 banks (2-way, free). Chunk swizzle pc = chunk ^ (((c>>3)^c)&3).
// Influence math in packed f16 (np stored as f16). dk stored f16.
// ---------------------------------------------------------------------------
__global__ __launch_bounds__(256, 4) void k_fused(
    const float* __restrict__ query, const float* __restrict__ support,
    const int* __restrict__ nidx, const _Float16* __restrict__ featH,
    const float* __restrict__ kpts, const float* __restrict__ obias,
    const _Float16* __restrict__ owt, const _Float16* __restrict__ wt,
    float* __restrict__ outx)
{
  __shared__ _Float16               nph[3][16][34];  // x/y/z, f16, pair-readable
  __shared__ unsigned short         sidx[16][34];
  __shared__ __align__(16) _Float16 fT[4][2048];     // per-wave, nbr 0..31
  __shared__ unsigned int           fx2[4][64];      // per-wave, (f32,f33) per c
  __shared__ __align__(16) _Float16 wfh[16 * 520];   // [pt][c'*16+k], half-K
  __shared__ _Float16               dkh[16][64];     // def_kp(45)+mod(15), f16

  const int tid  = threadIdx.x;
  const int wave = tid >> 6, lane = tid & 63;
  const int quad = lane >> 4, mm = lane & 15;
  const int base = blockIdx.x * 16;
  _Float16* fTw = fT[wave];
  unsigned int* fTw32 = (unsigned int*)fTw;
  unsigned int* fx2w = fx2[wave];
  const floatx4 fz = {0.f, 0.f, 0.f, 0.f};
  const int me = (mm < 15) ? mm : 14;   // row 15 of conv A is discarded

  // ---- stage neighbor displacements (f16) + indices ----
  for (int s = tid; s < 544; s += 256) {
    int pt = s / 34, a = s - pt * 34;
    int n = base + pt;
    int id = nidx[n * 34 + a];
    nph[0][pt][a] = (_Float16)(support[id * 3 + 0] - query[n * 3 + 0]);
    nph[1][pt][a] = (_Float16)(support[id * 3 + 1] - query[n * 3 + 1]);
    nph[2][pt][a] = (_Float16)(support[id * 3 + 2] - query[n * 3 + 2]);
    sidx[pt][a] = (unsigned short)id;
  }
  __syncthreads();

  // ---- gather loads (17 row-pairs x 8 chunks = 136 tasks) ----
  auto load_g = [&](int pl, uint4* g0, uint4* g1) {
    #pragma unroll
    for (int it = 0; it < 3; ++it) {
      int task = it * 64 + lane;
      if (task < 136) {
        int rp = task >> 3, ch = task & 7;
        int i0 = (int)sidx[pl][2 * rp], i1 = (int)sidx[pl][2 * rp + 1];
        g0[it] = *(const uint4*)(featH + i0 * 64 + ch * 8);
        g1[it] = *(const uint4*)(featH + i1 * 64 + ch * 8);
      }
    }
  };
  // ---- transpose staged regs -> fTw (rp<16, row-swizzled) / fx2w (rp==16) ----
  auto transpose_g = [&](const uint4* g0, const uint4* g1) {
    #pragma unroll
    for (int it = 0; it < 3; ++it) {
      int task = it * 64 + lane;
      if (task < 136) {
        int rp = task >> 3, ch = task & 7;
        const uint* p0 = (const uint*)&g0[it];
        const uint* p1 = (const uint*)&g1[it];
        if (rp < 16) {
          int chunk = rp >> 2, o = rp & 3;
          #pragma unroll
          for (int cc = 0; cc < 8; ++cc) {
            int c  = ch * 8 + cc;
            int pc = chunk ^ ((ch ^ cc) & 3);
            int rr = c ^ (ch & 1);          // row-parity swizzle
            uint v = __builtin_amdgcn_perm(p1[cc >> 1], p0[cc >> 1],
                                           (cc & 1) ? 0x07060302u : 0x05040100u);
            fTw32[rr * 16 + pc * 4 + o] = v;
          }
        } else {  // rows 32,33 -> fx2 (lo = f32[c], hi = f33[c])
          #pragma unroll
          for (int cc = 0; cc < 8; ++cc) {
            uint v = __builtin_amdgcn_perm(p1[cc >> 1], p0[cc >> 1],
                                           (cc & 1) ? 0x07060302u : 0x05040100u);
            fx2w[ch * 8 + cc] = v;
          }
        }
      }
    }
  };

  // ---- packed-f16 influence for one neighbor pair ----
  auto infl_pair = [&](int pl, int pj, half2v kx2, half2v ky2, half2v kz2,
                       _Float16& w0, _Float16& w1) {
    const half2v* px = (const half2v*)&nph[0][pl][0];
    const half2v* py = (const half2v*)&nph[1][pl][0];
    const half2v* pz = (const half2v*)&nph[2][pl][0];
    half2v dx = px[pj] - kx2, dy = py[pj] - ky2, dz = pz[pj] - kz2;
    half2v dd = dx * dx + dy * dy + dz * dz;
    _Float16 s0 = __builtin_sqrtf16(dd.x);
    _Float16 s1 = __builtin_sqrtf16(dd.y);
    _Float16 v0 = (_Float16)1.f - (_Float16)2.f * s0;
    _Float16 v1 = (_Float16)1.f - (_Float16)2.f * s1;
    w0 = (v0 > (_Float16)0.f) ? v0 : (_Float16)0.f;
    w1 = (v1 > (_Float16)0.f) ? v1 : (_Float16)0.f;
  };

  // ---- one conv point: 4 MFMA (nbr 0..31) + rank-2 (nbr 32,33), x mod.
  //      writes ct0/1 to wfh, returns ct2/3 in hold[2] ----
  auto conv_point = [&](int pl, _Float16 kxh, _Float16 kyh, _Float16 kzh,
                        const float* md, floatx4* hold) {
    half2v kx2 = {kxh, kxh}, ky2 = {kyh, kyh}, kz2 = {kzh, kzh};
    half8 a0;
    #pragma unroll
    for (int t = 0; t < 4; ++t) {
      _Float16 w0, w1;
      infl_pair(pl, quad * 4 + t, kx2, ky2, kz2, w0, w1);
      a0[2 * t] = w0; a0[2 * t + 1] = w1;
    }
    // rank-2 influence at kp=me (pair 16), redistribute via bpermute
    float w32, w33;
    {
      _Float16 w0, w1;
      infl_pair(pl, 16, kx2, ky2, kz2, w0, w1);
      w32 = (float)w0; w33 = (float)w1;
    }
    float w32r[4], w33r[4];
    #pragma unroll
    for (int r = 0; r < 4; ++r) {
      int src = (quad * 4 + r) << 2;
      w32r[r] = __int_as_float(__builtin_amdgcn_ds_bpermute(src, __float_as_int(w32)));
      w33r[r] = __int_as_float(__builtin_amdgcn_ds_bpermute(src, __float_as_int(w33)));
    }

    floatx4 acc[4];
    #pragma unroll
    for (int ct = 0; ct < 4; ++ct) {
      int c  = ct * 16 + mm;
      int rr = c ^ ((c >> 3) & 1);
      int pc = quad ^ (((c >> 3) ^ c) & 3);
      half8 b = *(const half8*)(fTw + rr * 32 + pc * 8);
      acc[ct] = __builtin_amdgcn_mfma_f32_16x16x32_f16(a0, b, fz, 0, 0, 0);
    }
    #pragma unroll
    for (int ct = 0; ct < 4; ++ct) {
      int c = ct * 16 + mm;
      uint fp = fx2w[c];
      _Float16 lo = __builtin_bit_cast(_Float16, (unsigned short)(fp & 0xffffu));
      _Float16 hi = __builtin_bit_cast(_Float16, (unsigned short)(fp >> 16));
      float flo = (float)lo, fhi = (float)hi;
      #pragma unroll
      for (int r = 0; r < 4; ++r)
        acc[ct][r] = (acc[ct][r] + w32r[r] * flo + w33r[r] * fhi) * md[r];
    }

    _Float16* wp = wfh + pl * 520;
    #pragma unroll
    for (int ct = 0; ct < 2; ++ct) {
      half4 h = {(_Float16)acc[ct][0], (_Float16)acc[ct][1],
                 (_Float16)acc[ct][2], (_Float16)acc[ct][3]};
      *(half4*)(wp + (ct * 16 + mm) * 16 + quad * 4) = h;
    }
    hold[0] = acc[2]; hold[1] = acc[3];
  };

  // ---- write held ct2/3 accs into wfh (phase B) ----
  auto write_hold = [&](const floatx4 (*hold)[2]) {
    #pragma unroll
    for (int pp = 0; pp < 4; ++pp) {
      _Float16* wp = wfh + (wave * 4 + pp) * 520;
      #pragma unroll
      for (int ct = 0; ct < 2; ++ct) {
        const floatx4& a = hold[pp][ct];
        half4 h = {(_Float16)a[0], (_Float16)a[1], (_Float16)a[2], (_Float16)a[3]};
        *(half4*)(wp + (ct * 16 + mm) * 16 + quad * 4) = h;
      }
    }
  };

  // ---- half-K GEMM: 16 k-steps vs bmat rows [64][1024], offset 0 or 512 ----
  auto gemm_half = [&](const _Float16* bmat, int koff, floatx4& A, floatx4& B) {
    const _Float16* brow = bmat + (wave * 16 + mm) * 1024 + koff;
    const _Float16* arow = wfh + mm * 520;
    #pragma unroll
    for (int k2 = 0; k2 < 16; ++k2) {
      half8 af = *(const half8*)(arow + k2 * 32 + quad * 8);
      half8 bf = *(const half8*)(brow + k2 * 32 + quad * 8);
      if (k2 & 1) B = __builtin_amdgcn_mfma_f32_16x16x32_f16(af, bf, B, 0, 0, 0);
      else        A = __builtin_amdgcn_mfma_f32_16x16x32_f16(af, bf, A, 0, 0, 0);
    }
  };

  uint4 G0[2][3], G1[2][3];
  floatx4 hold[4][2];
  const float one4[4] = {1.f, 1.f, 1.f, 1.f};

  // ================= conv0 (rigid kernel points) =================
  {
    _Float16 k0x = (_Float16)kpts[me * 3 + 0];
    _Float16 k0y = (_Float16)kpts[me * 3 + 1];
    _Float16 k0z = (_Float16)kpts[me * 3 + 2];
    load_g(wave * 4, G0[0], G1[0]);
    #pragma unroll
    for (int pp = 0; pp < 4; ++pp) {
      int pl = wave * 4 + pp;
      if (pp < 3) load_g(pl + 1, G0[(pp + 1) & 1], G1[(pp + 1) & 1]);
      transpose_g(G0[pp & 1], G1[pp & 1]);
      conv_point(pl, k0x, k0y, k0z, one4, hold[pp]);
    }
  }
  load_g(wave * 4, G0[0], G1[0]);   // prefetch conv1 p0 under GEMM0
  __syncthreads();

  // ================= GEMM0 (2 phases) -> def_kp + modulations =================
  {
    floatx4 A = fz, B = fz;
    gemm_half(owt, 0, A, B);
    __syncthreads();
    write_hold(hold);
    __syncthreads();
    gemm_half(owt, 512, A, B);
    int d = wave * 16 + mm;
    float bv = (d < 60) ? obias[d] : 0.f;
    float kv = (d < 45) ? kpts[d] : 0.f;
    #pragma unroll
    for (int r = 0; r < 4; ++r) {
      int pt = quad * 4 + r;
      float v = A[r] + B[r] + bv;
      float o = (d < 45) ? (kv + 0.5f * v)            // def_kp = kp + f0*EXTENT
                         : (2.f / (1.f + expf(-v)));  // modulation
      dkh[pt][d] = (_Float16)o;
    }
  }
  __syncthreads();   // dk ready; GEMM0 wfh reads done

  // ================= conv1 (deformed kernel points) =================
  #pragma unroll
  for (int pp = 0; pp < 4; ++pp) {
    int pl = wave * 4 + pp;
    if (pp < 3) load_g(pl + 1, G0[(pp + 1) & 1], G1[(pp + 1) & 1]);
    _Float16 kx = dkh[pl][me * 3 + 0];
    _Float16 ky = dkh[pl][me * 3 + 1];
    _Float16 kz = dkh[pl][me * 3 + 2];
    float md[4];
    #pragma unroll
    for (int r = 0; r < 4; ++r) {
      int k = quad * 4 + r;
      md[r] = (k < 15) ? (float)dkh[pl][45 + k] : 1.f;
    }
    transpose_g(G0[pp & 1], G1[pp & 1]);
    conv_point(pl, kx, ky, kz, md, hold[pp]);
  }
  __syncthreads();

  // ================= GEMM1 (2 phases) -> x (pre-BN) =================
  {
    floatx4 A = fz, B = fz;
    gemm_half(wt, 0, A, B);
    __syncthreads();
    write_hold(hold);
    __syncthreads();
    gemm_half(wt, 512, A, B);
    int d = wave * 16 + mm;
    #pragma unroll
    for (int r = 0; r < 4; ++r)
      outx[(base + quad * 4 + r) * 64 + d] = A[r] + B[r];
  }
}

// ---------------------------------------------------------------------------
// Per-channel partial sums (no atomics): part[b][0..63]=sum, [64..127]=sumsq
// ---------------------------------------------------------------------------
__global__ __launch_bounds__(256) void k_stats(
    const float* __restrict__ x, float* __restrict__ part)
{
  __shared__ float red[512];
  const int tid = threadIdx.x;
  const int c = tid & 63, g = tid >> 6;
  float s1 = 0.f, s2 = 0.f;
  for (int r = blockIdx.x * 4 + g; r < NPTS; r += 512) {
    float v = x[r * 64 + c];
    s1 += v; s2 += v * v;
  }
  red[tid] = s1; red[256 + tid] = s2;
  __syncthreads();
  if (tid < 64) {
    s1 = red[tid] + red[tid + 64] + red[tid + 128] + red[tid + 192];
    s2 = red[256 + tid] + red[256 + tid + 64] + red[256 + tid + 128] + red[256 + tid + 192];
    part[blockIdx.x * 128 + c] = s1;
    part[blockIdx.x * 128 + 64 + c] = s2;
  }
}

// ---------------------------------------------------------------------------
// Reduce 128 partials -> stats[0..127]
// ---------------------------------------------------------------------------
__global__ __launch_bounds__(256) void k_reduce(
    const float* __restrict__ part, float* __restrict__ stats)
{
  __shared__ float red[256];
  const int tid = threadIdx.x;
  const int c = tid & 127, half = tid >> 7;
  float s = 0.f;
  #pragma unroll 4
  for (int b = half * 64; b < half * 64 + 64; ++b) s += part[b * 128 + c];
  red[tid] = s;
  __syncthreads();
  if (tid < 128) stats[tid] = red[tid] + red[tid + 128];
}

// ---------------------------------------------------------------------------
// BN (batch stats, biased var, eps=1e-6) + LeakyReLU(0.1), in-place
// ---------------------------------------------------------------------------
__global__ __launch_bounds__(256) void k_norm(
    float* __restrict__ x, const float* __restrict__ stats,
    const float* __restrict__ gamma, const float* __restrict__ beta)
{
  const int i = blockIdx.x * 256 + threadIdx.x;
  float4 v = ((float4*)x)[i];
  const int c0 = (i * 4) & 63;
  float o[4] = {v.x, v.y, v.z, v.w};
  #pragma unroll
  for (int j = 0; j < 4; ++j) {
    int c = c0 + j;
    float mean = stats[c] * (1.f / NPTS);
    float var  = stats[64 + c] * (1.f / NPTS) - mean * mean;
    float s = rsqrtf(var + 1e-6f) * gamma[c];
    float y = (o[j] - mean) * s + beta[c];
    o[j] = (y >= 0.f) ? y : 0.1f * y;
  }
  float4 rv = {o[0], o[1], o[2], o[3]};
  ((float4*)x)[i] = rv;
}

// ---------------------------------------------------------------------------
extern "C" void kernel_launch(void* const* d_in, const int* in_sizes, int n_in,
                              void* d_out, int out_size, void* d_ws, size_t ws_size,
                              hipStream_t stream)
{
  const float* query   = (const float*)d_in[0];
  const float* support = (const float*)d_in[1];
  const int*   nidx    = (const int*)d_in[2];
  const float* feat    = (const float*)d_in[3];
  const float* weight  = (const float*)d_in[4];
  const float* oweight = (const float*)d_in[5];
  const float* obias   = (const float*)d_in[6];
  const float* gamma   = (const float*)d_in[7];
  const float* beta    = (const float*)d_in[8];
  const float* kpts    = (const float*)d_in[9];
  float* x = (float*)d_out;

  char* ws = (char*)d_ws;
  _Float16* featH = (_Float16*)ws;                  // 8,388,608 B
  _Float16* owt   = (_Float16*)(ws + 8388608);      //   131,072 B
  _Float16* wt    = (_Float16*)(ws + 8519680);      //   131,072 B
  float*    part  = (float*)(ws + 8650752);         //    65,536 B
  float*    stats = (float*)(ws + 8716288);         //       512 B

  k_prep<<<4352, 256, 0, stream>>>(oweight, weight, feat, owt, wt, featH);
  k_fused<<<4096, 256, 0, stream>>>(query, support, nidx, featH, kpts, obias,
                                    owt, wt, x);
  k_stats<<<128, 256, 0, stream>>>(x, part);
  k_reduce<<<1, 256, 0, stream>>>(part, stats);
  k_norm<<<4096, 256, 0, stream>>>(x, stats, gamma, beta);
}